// Round 16
// baseline (77.305 us; speedup 1.0000x reference)
//
#include <hip/hip_runtime.h>
#include <hip/hip_bf16.h>
#include <stdint.h>

#define N_W 96
#define NAG 192                      // total agents
#define NP1 97
#define W_ELEMS (N_W * NP1 * NP1)    // 903264 (divisible by 4)
#define R_ELEMS (NAG * NAG)          // 36864
#define WB ((W_ELEMS / 4 + 255) / 256)   // 883
#define RB ((R_ELEMS / 4 + 255) / 256)   // 36

// Decode one-hot tensors into packed index form + dictation times.
__global__ __launch_bounds__(256) void decode_kernel(
    const float* __restrict__ W, const float* __restrict__ F,
    const float* __restrict__ R,
    short* __restrict__ ps, short* __restrict__ ord, short* __restrict__ td) {
    int b = blockIdx.x;
    if (b < 2 * WB) {
        const float* src = (b < WB) ? W : F;
        int abase = (b < WB) ? 0 : N_W;
        int i4 = (b - ((b < WB) ? 0 : WB)) * 256 + threadIdx.x;
        if (i4 < W_ELEMS / 4) {
            float4 v = ((const float4*)src)[i4];
            int base = i4 * 4;
            #pragma unroll
            for (int u = 0; u < 4; ++u) {
                float x = (u == 0) ? v.x : (u == 1) ? v.y : (u == 2) ? v.z : v.w;
                if (x > 0.5f) {
                    int idx = base + u;
                    int a = idx / (NP1 * NP1);
                    int rem = idx - a * (NP1 * NP1);
                    int j = rem / NP1;          // option (or 96=unmatch)
                    int k = rem - j * NP1;      // rank
                    int slot = (k < 64) ? (2 * k) : (2 * (k - 64) + 1);
                    ps[(abase + a) * 128 + slot] = (short)j;
                }
            }
        }
    } else {
        int i4 = (b - 2 * WB) * 256 + threadIdx.x;
        if (i4 < R_ELEMS / 4) {
            float4 v = ((const float4*)R)[i4];
            int base = i4 * 4;
            #pragma unroll
            for (int u = 0; u < 4; ++u) {
                float x = (u == 0) ? v.x : (u == 1) ? v.y : (u == 2) ? v.z : v.w;
                if (x > 0.5f) {
                    int idx = base + u;
                    int a = idx / NAG;
                    int r = idx - a * NAG;
                    ord[r] = (short)a;
                    td[a] = (short)r;
                }
            }
        }
    }
}

// Single-block sequential serial dictatorship.
// Branch-free common path: uniform s_cselect routing, bitset+clear trick for
// unmatch, dead rounds redirected to harmless bit 127. ord via s_load (no
// readlane hop); prefs via interleaved group-of-4 ds_read_b128, block-ahead.
__global__ __launch_bounds__(256, 1) void sd_kernel(
    const uint32_t* __restrict__ pk_g, const short* __restrict__ ord_g,
    const short* __restrict__ td_g, float* __restrict__ out) {
    __shared__ __align__(16) uint4 s_pk4[52 * 64];   // 48 groups + 4 pad
    __shared__ uint32_t s_match[NAG];
    __shared__ unsigned short s_og[NAG];
    __shared__ unsigned short s_td[NAG];

    const int t = threadIdx.x;
    if (t < NAG) {
        s_og[t] = ((const unsigned short*)ord_g)[t];
        s_td[t] = ((const unsigned short*)td_g)[t];
    }
    __syncthreads();

    // staging: s_pk4[g*64+lane] = {baked P[4g+i][lane]}_{i=0..3}
    // bake: pref j -> 97 (always-unavailable sentinel) if its owner dictates
    // before round r.
    for (int idx = t; idx < 48 * 64; idx += 256) {
        int g = idx >> 6, ln = idx & 63;
        uint32_t w[4];
        #pragma unroll
        for (int i = 0; i < 4; ++i) {
            int r = 4 * g + i;
            int a = (int)s_og[r];
            uint32_t x = pk_g[(a << 6) + ln];        // coalesced per (g,i)
            int opp = (a < 96) ? 96 : 0;
            uint32_t j1 = x & 0xFFFFu, j2 = x >> 16;
            if (j1 < 96u && (int)s_td[opp + j1] < r) j1 = 97u;
            if (j2 < 96u && (int)s_td[opp + j2] < r) j2 = 97u;
            w[i] = j1 | (j2 << 16);
        }
        s_pk4[idx] = make_uint4(w[0], w[1], w[2], w[3]);
    }
    __syncthreads();

    if (t < 64) {
        // chosen-only masks; bit33(hi) = sentinel-97 permanently unavailable;
        // bit32(hi) = option 96 (unmatch) kept clear by invariant.
        uint64_t chWlo = 0, chWhi = (1ull << 33), chFlo = 0, chFhi = (1ull << 33);
        uint32_t c0 = 0xFFFFFFFFu, c1 = 0xFFFFFFFFu, c2 = 0xFFFFFFFFu;
        const uint4* ordq = (const uint4*)ord_g;

        auto ROUND = [&](uint32_t P, int a, uint32_t rr64, uint32_t& cv) {
            // uniform pre-selects (SALU cselect)
            uint32_t aa = (a < 96) ? (uint32_t)a : (uint32_t)(a - 96);
            uint64_t own = (a < 96) ? ((aa < 64u) ? chWlo : chWhi)
                                    : ((aa < 64u) ? chFlo : chFhi);
            uint32_t dead = (uint32_t)((own >> (aa & 63u)) & 1ull);
            uint64_t olo = (a < 96) ? chFlo : chWlo;
            uint64_t ohi = (a < 96) ? chFhi : chWhi;
            // per-lane availability test (VALU; SGPR-pair operands are free)
            uint32_t j1 = P & 0xFFFFu;
            uint32_t b1 = (uint32_t)(((j1 < 64u) ? (olo >> (j1 & 63u))
                                                 : (ohi >> (j1 & 63u))) & 1ull);
            unsigned long long m1 = __ballot(b1 == 0u);
            uint32_t js;
            if (__builtin_expect(m1 != 0ull, 1)) {
                int k = __ffsll(m1) - 1;
                js = ((uint32_t)__builtin_amdgcn_readlane((int)P, k)) & 0xFFFFu;
            } else {                                  // cold: rank>=64
                uint32_t j2 = P >> 16;
                uint32_t b2 = (uint32_t)(((j2 < 64u) ? (olo >> (j2 & 63u))
                                                     : (ohi >> (j2 & 63u))) & 1ull);
                unsigned long long m2 = __ballot(b2 == 0u) & 0x1FFFFFFFFull;
                int k2 = __ffsll(m2) - 1;
                js = ((uint32_t)__builtin_amdgcn_readlane((int)P, k2)) >> 16;
            }
            // branchless update: dead -> harmless bit 127; unmatch(96) cleared after
            uint32_t js_eff = dead ? 127u : js;
            uint64_t sb = 1ull << (js_eff & 63u);
            uint64_t nlo = olo | ((js_eff < 64u) ? sb : 0ull);
            uint64_t nhi = (ohi | ((js_eff < 64u) ? 0ull : sb)) & ~(1ull << 32);
            chWlo = (a < 96) ? chWlo : nlo;  chWhi = (a < 96) ? chWhi : nhi;
            chFlo = (a < 96) ? nlo : chFlo;  chFhi = (a < 96) ? nhi : chFhi;
            uint32_t rowf = (a < 96) ? (uint32_t)a : js;
            uint32_t colt = (a < 96) ? js : aa;
            uint32_t cell = dead ? 0xFFFFFFFFu : (rowf * (uint32_t)NP1 + colt);
            cv = (t == (int)rr64) ? cell : cv;        // lane-capture (off-chain)
        };

        auto SEG = [&](int seg, uint32_t& cv) {
            uint4 Qa0 = s_pk4[(seg * 16 + 0) * 64 + t];
            uint4 Qa1 = s_pk4[(seg * 16 + 1) * 64 + t];
            uint4 Qa2 = s_pk4[(seg * 16 + 2) * 64 + t];
            uint4 Qa3 = s_pk4[(seg * 16 + 3) * 64 + t];
            uint4 oA = ordq[seg * 8 + 0], oB = ordq[seg * 8 + 1];
            #pragma clang loop unroll(disable)
            for (int blk = 0; blk < 4; ++blk) {
                int bi = seg * 4 + blk;
                uint4 Qn0 = s_pk4[(bi * 4 + 4) * 64 + t];   // next-block prefetch
                uint4 Qn1 = s_pk4[(bi * 4 + 5) * 64 + t];
                uint4 Qn2 = s_pk4[(bi * 4 + 6) * 64 + t];
                uint4 Qn3 = s_pk4[(bi * 4 + 7) * 64 + t];
                uint4 oA2 = ordq[2 * bi + 2], oB2 = ordq[2 * bi + 3];
                uint32_t rb = (uint32_t)(blk * 16);
                ROUND(Qa0.x, (int)(oA.x & 0xFFFFu), rb + 0, cv);
                ROUND(Qa0.y, (int)(oA.x >> 16),     rb + 1, cv);
                ROUND(Qa0.z, (int)(oA.y & 0xFFFFu), rb + 2, cv);
                ROUND(Qa0.w, (int)(oA.y >> 16),     rb + 3, cv);
                ROUND(Qa1.x, (int)(oA.z & 0xFFFFu), rb + 4, cv);
                ROUND(Qa1.y, (int)(oA.z >> 16),     rb + 5, cv);
                ROUND(Qa1.z, (int)(oA.w & 0xFFFFu), rb + 6, cv);
                ROUND(Qa1.w, (int)(oA.w >> 16),     rb + 7, cv);
                ROUND(Qa2.x, (int)(oB.x & 0xFFFFu), rb + 8, cv);
                ROUND(Qa2.y, (int)(oB.x >> 16),     rb + 9, cv);
                ROUND(Qa2.z, (int)(oB.y & 0xFFFFu), rb + 10, cv);
                ROUND(Qa2.w, (int)(oB.y >> 16),     rb + 11, cv);
                ROUND(Qa3.x, (int)(oB.z & 0xFFFFu), rb + 12, cv);
                ROUND(Qa3.y, (int)(oB.z >> 16),     rb + 13, cv);
                ROUND(Qa3.z, (int)(oB.w & 0xFFFFu), rb + 14, cv);
                ROUND(Qa3.w, (int)(oB.w >> 16),     rb + 15, cv);
                Qa0 = Qn0; Qa1 = Qn1; Qa2 = Qn2; Qa3 = Qn3;
                oA = oA2; oB = oB2;
            }
        };
        SEG(0, c0);
        SEG(1, c1);
        SEG(2, c2);
        s_match[t] = c0; s_match[64 + t] = c1; s_match[128 + t] = c2;
    } else {
        // waves 1-3: zero-fill output concurrently with wave 0's loop
        for (int i = t - 64; i < 2352; i += 192)
            ((float4*)out)[i] = make_float4(0.f, 0.f, 0.f, 0.f);
        if (t == 64) out[9408] = 0.f;
    }
    __syncthreads();
    if (t < NAG) {
        uint32_t c = s_match[t];
        if (c != 0xFFFFFFFFu) out[c] = 1.0f;
    }
}

extern "C" void kernel_launch(void* const* d_in, const int* in_sizes, int n_in,
                              void* d_out, int out_size, void* d_ws, size_t ws_size,
                              hipStream_t stream) {
    const float* W = (const float*)d_in[0];
    const float* F = (const float*)d_in[1];
    const float* R = (const float*)d_in[2];
    float* out = (float*)d_out;

    uint32_t* packed = (uint32_t*)d_ws;                      // NAG*64 u32 = 48 KiB
    short* ord = (short*)((char*)d_ws + NAG * 64 * 4);       // 192 shorts
    short* td  = (short*)((char*)d_ws + NAG * 64 * 4 + NAG * 2);  // 192 shorts

    decode_kernel<<<2 * WB + RB, 256, 0, stream>>>(W, F, R, (short*)packed, ord, td);
    sd_kernel<<<1, 256, 0, stream>>>(packed, ord, td, out);
}

// Round 17
// 76.226 us; speedup vs baseline: 1.0141x; 1.0141x over previous
//
#include <hip/hip_runtime.h>
#include <hip/hip_bf16.h>
#include <stdint.h>

#define N_W 96
#define NAG 192                      // total agents
#define NP1 97
#define W_ELEMS (N_W * NP1 * NP1)    // 903264 (divisible by 4)
#define R_ELEMS (NAG * NAG)          // 36864
#define WB ((W_ELEMS / 4 + 255) / 256)   // 883
#define RB ((R_ELEMS / 4 + 255) / 256)   // 36

// Decode one-hot tensors into packed index form + dictation times.
__global__ __launch_bounds__(256) void decode_kernel(
    const float* __restrict__ W, const float* __restrict__ F,
    const float* __restrict__ R,
    short* __restrict__ ps, short* __restrict__ ord, short* __restrict__ td) {
    int b = blockIdx.x;
    if (b < 2 * WB) {
        const float* src = (b < WB) ? W : F;
        int abase = (b < WB) ? 0 : N_W;
        int i4 = (b - ((b < WB) ? 0 : WB)) * 256 + threadIdx.x;
        if (i4 < W_ELEMS / 4) {
            float4 v = ((const float4*)src)[i4];
            int base = i4 * 4;
            #pragma unroll
            for (int u = 0; u < 4; ++u) {
                float x = (u == 0) ? v.x : (u == 1) ? v.y : (u == 2) ? v.z : v.w;
                if (x > 0.5f) {
                    int idx = base + u;
                    int a = idx / (NP1 * NP1);
                    int rem = idx - a * (NP1 * NP1);
                    int j = rem / NP1;          // option (or 96=unmatch)
                    int k = rem - j * NP1;      // rank
                    int slot = (k < 64) ? (2 * k) : (2 * (k - 64) + 1);
                    ps[(abase + a) * 128 + slot] = (short)j;
                }
            }
        }
    } else {
        int i4 = (b - 2 * WB) * 256 + threadIdx.x;
        if (i4 < R_ELEMS / 4) {
            float4 v = ((const float4*)R)[i4];
            int base = i4 * 4;
            #pragma unroll
            for (int u = 0; u < 4; ++u) {
                float x = (u == 0) ? v.x : (u == 1) ? v.y : (u == 2) ? v.z : v.w;
                if (x > 0.5f) {
                    int idx = base + u;
                    int a = idx / NAG;
                    int r = idx - a * NAG;
                    ord[r] = (short)a;
                    td[a] = (short)r;
                }
            }
        }
    }
}

// min(kk, dpp_shifted(kk)) — pure VALU, no SALU crossing
#define DPPMIN(ctrl) do {                                                     \
    uint32_t y_ = (uint32_t)__builtin_amdgcn_update_dpp(                      \
        (int)kk, (int)kk, (ctrl), 0xF, 0xF, false);                           \
    kk = (kk < y_) ? kk : y_;                                                 \
} while (0)

// Single-block sequential serial dictatorship.
// Selection via DPP min-reduce over keys (rank<<7|option): no ballot/ffs,
// no cold path; one readlane hop per round. Baked static removals (97
// sentinel), chosen-only SGPR masks, group-of-4 interleaved pref loads.
__global__ __launch_bounds__(256, 1) void sd_kernel(
    const uint32_t* __restrict__ pk_g, const short* __restrict__ ord_g,
    const short* __restrict__ td_g, float* __restrict__ out) {
    __shared__ __align__(16) uint4 s_pk4[49 * 64];   // 48 groups + 1 pad
    __shared__ uint32_t s_match[NAG];
    __shared__ unsigned short s_og[NAG];
    __shared__ unsigned short s_td[NAG];

    const int t = threadIdx.x;
    if (t < NAG) {
        s_og[t] = ((const unsigned short*)ord_g)[t];
        s_td[t] = ((const unsigned short*)td_g)[t];
    }
    __syncthreads();

    // staging: s_pk4[g*64+lane] = {baked P[4g+i][lane]}_{i=0..3}
    for (int idx = t; idx < 48 * 64; idx += 256) {
        int g = idx >> 6, ln = idx & 63;
        uint32_t w[4];
        #pragma unroll
        for (int i = 0; i < 4; ++i) {
            int r = 4 * g + i;
            int a = (int)s_og[r];
            uint32_t x = pk_g[(a << 6) + ln];
            int opp = (a < 96) ? 96 : 0;
            uint32_t j1 = x & 0xFFFFu, j2 = x >> 16;
            if (j1 < 96u && (int)s_td[opp + j1] < r) j1 = 97u;
            if (j2 < 96u && (int)s_td[opp + j2] < r) j2 = 97u;
            w[i] = j1 | (j2 << 16);
        }
        s_pk4[idx] = make_uint4(w[0], w[1], w[2], w[3]);
    }
    __syncthreads();

    if (t < 64) {
        // chosen-only masks; bit33(hi)=sentinel-97 always unavailable;
        // bit32(hi)=unmatch(96) kept clear by invariant.
        uint64_t chWlo = 0, chWhi = (1ull << 33), chFlo = 0, chFhi = (1ull << 33);
        const uint64_t clr32 = (1ull << 32);
        const uint32_t lane2inv = (t < 33) ? 0u : 1u;   // slot2 valid lanes 0..32
        const uint4* ordq = (const uint4*)ord_g;        // uniform s_load

        auto ROUND = [&](uint32_t P, uint32_t a, int r) {
            // per-lane statics (off-chain)
            uint32_t j1 = P & 0xFFFFu, j2 = P >> 16;
            uint32_t key1 = ((uint32_t)t << 7) | j1;
            uint32_t key2 = (((uint32_t)t + 64u) << 7) | (j2 & 127u);
            uint32_t l1 = (j1 < 64u) ? 1u : 0u, h1 = 1u - l1;
            uint32_t l2 = (j2 < 64u) ? 1u : 0u, h2 = 1u - l2;
            // uniform scalars (SALU; dead-chain overlaps VALU phase)
            uint32_t isW = (a < 96u) ? 1u : 0u;
            uint32_t aa = isW ? a : (a - 96u);
            uint64_t olo = isW ? chFlo : chWlo;
            uint64_t ohi = isW ? chFhi : chWhi;
            uint64_t ownw = isW ? ((aa < 64u) ? chWlo : chWhi)
                                : ((aa < 64u) ? chFlo : chFhi);
            uint32_t dead = (uint32_t)((ownw >> (aa & 63u)) & 1ull);
            // per-lane availability -> keys -> DPP min (pure VALU)
            uint32_t b1 = (((uint32_t)(olo >> (j1 & 63u))) & l1)
                        | (((uint32_t)(ohi >> (j1 & 63u))) & h1);
            uint32_t b2 = ((((uint32_t)(olo >> (j2 & 63u))) & l2)
                        | (((uint32_t)(ohi >> (j2 & 63u))) & h2)) | lane2inv;
            uint32_t kk1 = b1 ? 0x7FFFFFFFu : key1;
            uint32_t kk2 = b2 ? 0x7FFFFFFFu : key2;
            uint32_t kk = (kk1 < kk2) ? kk1 : kk2;
            DPPMIN(0x111);   // row_shr:1
            DPPMIN(0x112);   // row_shr:2
            DPPMIN(0x114);   // row_shr:4
            DPPMIN(0x118);   // row_shr:8
            DPPMIN(0x142);   // row_bcast:15
            DPPMIN(0x143);   // row_bcast:31
            uint32_t key = (uint32_t)__builtin_amdgcn_readlane((int)kk, 63);
            // SALU tail
            uint32_t js = key & 127u;
            uint32_t js_eff = dead ? 127u : js;      // dead -> harmless bit 63(hi)
            uint64_t sb = 1ull << (js_eff & 63u);
            uint64_t nlo = olo | ((js_eff < 64u) ? sb : 0ull);
            uint64_t nhi = (ohi | ((js_eff < 64u) ? 0ull : sb)) & ~clr32;
            chWlo = isW ? chWlo : nlo;  chWhi = isW ? chWhi : nhi;
            chFlo = isW ? nlo : chFlo;  chFhi = isW ? nhi : chFhi;
            uint32_t cell = isW ? (a * 97u + js) : (js * 97u + aa);
            s_match[r] = dead ? 0xFFFFFFFFu : cell;  // all-lane uniform write
        };

        uint4 Q = s_pk4[t];
        uint4 oq = ordq[0];
        uint4 oqn = oq;
        #pragma clang loop unroll(disable)
        for (int g = 0; g < 48; ++g) {
            uint4 Qn = s_pk4[(g + 1) * 64 + t];      // next-group pref prefetch
            uint32_t w0, w1;
            if (!(g & 1)) {
                w0 = oq.x; w1 = oq.y;
                oqn = ordq[(g >> 1) + 1];            // prefetch 2 groups ahead
            } else {
                w0 = oq.z; w1 = oq.w;
                oq = oqn;
            }
            ROUND(Q.x, w0 & 0xFFFFu, 4 * g + 0);
            ROUND(Q.y, w0 >> 16,     4 * g + 1);
            ROUND(Q.z, w1 & 0xFFFFu, 4 * g + 2);
            ROUND(Q.w, w1 >> 16,     4 * g + 3);
            Q = Qn;
        }
    } else {
        // waves 1-3: zero-fill output concurrently with wave 0's loop
        for (int i = t - 64; i < 2352; i += 192)
            ((float4*)out)[i] = make_float4(0.f, 0.f, 0.f, 0.f);
        if (t == 64) out[9408] = 0.f;
    }
    __syncthreads();
    if (t < NAG) {
        uint32_t c = s_match[t];
        if (c != 0xFFFFFFFFu) out[c] = 1.0f;
    }
}

extern "C" void kernel_launch(void* const* d_in, const int* in_sizes, int n_in,
                              void* d_out, int out_size, void* d_ws, size_t ws_size,
                              hipStream_t stream) {
    const float* W = (const float*)d_in[0];
    const float* F = (const float*)d_in[1];
    const float* R = (const float*)d_in[2];
    float* out = (float*)d_out;

    uint32_t* packed = (uint32_t*)d_ws;                      // NAG*64 u32 = 48 KiB
    short* ord = (short*)((char*)d_ws + NAG * 64 * 4);       // 192 shorts
    short* td  = (short*)((char*)d_ws + NAG * 64 * 4 + NAG * 2);  // 192 shorts

    decode_kernel<<<2 * WB + RB, 256, 0, stream>>>(W, F, R, (short*)packed, ord, td);
    sd_kernel<<<1, 256, 0, stream>>>(packed, ord, td, out);
}

// Round 18
// 71.368 us; speedup vs baseline: 1.0832x; 1.0681x over previous
//
#include <hip/hip_runtime.h>
#include <hip/hip_bf16.h>
#include <stdint.h>

#define N_W 96
#define NAG 192                      // total agents
#define NP1 97
#define W_ELEMS (N_W * NP1 * NP1)    // 903264 (divisible by 4)
#define R_ELEMS (NAG * NAG)          // 36864
#define WB ((W_ELEMS / 4 + 255) / 256)   // 883
#define RB ((R_ELEMS / 4 + 255) / 256)   // 36

// Decode one-hot tensors into packed index form + dictation times.
__global__ __launch_bounds__(256) void decode_kernel(
    const float* __restrict__ W, const float* __restrict__ F,
    const float* __restrict__ R,
    short* __restrict__ ps, short* __restrict__ ord, short* __restrict__ td) {
    int b = blockIdx.x;
    if (b < 2 * WB) {
        const float* src = (b < WB) ? W : F;
        int abase = (b < WB) ? 0 : N_W;
        int i4 = (b - ((b < WB) ? 0 : WB)) * 256 + threadIdx.x;
        if (i4 < W_ELEMS / 4) {
            float4 v = ((const float4*)src)[i4];
            int base = i4 * 4;
            #pragma unroll
            for (int u = 0; u < 4; ++u) {
                float x = (u == 0) ? v.x : (u == 1) ? v.y : (u == 2) ? v.z : v.w;
                if (x > 0.5f) {
                    int idx = base + u;
                    int a = idx / (NP1 * NP1);
                    int rem = idx - a * (NP1 * NP1);
                    int j = rem / NP1;          // option (or 96=unmatch)
                    int k = rem - j * NP1;      // rank
                    int slot = (k < 64) ? (2 * k) : (2 * (k - 64) + 1);
                    ps[(abase + a) * 128 + slot] = (short)j;
                }
            }
        }
    } else {
        int i4 = (b - 2 * WB) * 256 + threadIdx.x;
        if (i4 < R_ELEMS / 4) {
            float4 v = ((const float4*)R)[i4];
            int base = i4 * 4;
            #pragma unroll
            for (int u = 0; u < 4; ++u) {
                float x = (u == 0) ? v.x : (u == 1) ? v.y : (u == 2) ? v.z : v.w;
                if (x > 0.5f) {
                    int idx = base + u;
                    int a = idx / NAG;
                    int r = idx - a * NAG;
                    ord[r] = (short)a;
                    td[a] = (short)r;
                }
            }
        }
    }
}

// dictator ids for a group of 8 (uniform SALU extracts)
#define AEXT(ov_) \
    const uint32_t A0 = (ov_).x & 0xFFFFu, A1 = (ov_).x >> 16, \
                   A2 = (ov_).y & 0xFFFFu, A3 = (ov_).y >> 16, \
                   A4 = (ov_).z & 0xFFFFu, A5 = (ov_).z >> 16, \
                   A6 = (ov_).w & 0xFFFFu, A7 = (ov_).w >> 16;

// Phase A: speculative slot-1 query for round q from GROUP-START masks.
// Independent across q -> ballot/ffs/readlane hops pipeline.
#define QPH(q, P_) \
    const uint32_t j1_##q = (P_) & 0xFFFFu; \
    const uint64_t slo_##q = (A##q < 96u) ? chFlo : chWlo; \
    const uint64_t shi_##q = (A##q < 96u) ? chFhi : chWhi; \
    const uint32_t w1_##q = (uint32_t)((((j1_##q < 64u) ? slo_##q : shi_##q) \
                                        >> (j1_##q & 63u)) & 1ull); \
    const unsigned long long m1_##q = __ballot(w1_##q == 0u); \
    const bool z_##q = (m1_##q == 0ull); \
    const int k_##q = __ffsll(m1_##q) - 1; \
    const uint32_t js0_##q = ((uint32_t)__builtin_amdgcn_readlane( \
        (int)(P_), k_##q & 63)) & 0xFFFFu;

// Phase B: lean scalar resolve; ONLY branch = rare z/collision requery.
#define RESQ(q, P_, rr) do { \
    const uint32_t a_ = A##q; \
    const uint32_t isW_ = (a_ < 96u) ? 1u : 0u; \
    const uint32_t aa_ = isW_ ? a_ : (a_ - 96u); \
    const uint64_t own_ = isW_ ? ((aa_ < 64u) ? chWlo : chWhi) \
                               : ((aa_ < 64u) ? chFlo : chFhi); \
    const uint32_t dead_ = (uint32_t)((own_ >> (aa_ & 63u)) & 1ull); \
    const uint64_t olo_ = isW_ ? chFlo : chWlo; \
    const uint64_t ohi_ = isW_ ? chFhi : chWhi; \
    uint32_t js_ = js0_##q; \
    const bool coll_ = z_##q | \
        (((((js_ < 64u) ? olo_ : ohi_) >> (js_ & 63u)) & 1ull) != 0ull); \
    if (__builtin_expect(coll_, 0)) js_ = FULLQ(P_, olo_, ohi_); \
    const uint32_t je_ = dead_ ? 127u : js_; \
    const uint64_t sb_ = 1ull << (je_ & 63u); \
    const uint64_t nlo_ = olo_ | ((je_ < 64u) ? sb_ : 0ull); \
    const uint64_t nhi_ = (ohi_ | ((je_ < 64u) ? 0ull : sb_)) & ~(1ull << 32); \
    chWlo = isW_ ? chWlo : nlo_;  chWhi = isW_ ? chWhi : nhi_; \
    chFlo = isW_ ? nlo_ : chFlo;  chFhi = isW_ ? nhi_ : chFhi; \
    uint32_t cell_ = isW_ ? (a_ * 97u + js_) : (js_ * 97u + aa_); \
    cell_ = dead_ ? 0xFFFFFFFFu : cell_; \
    cv = (t == (int)(rr)) ? cell_ : cv; \
} while (0)

// Single-block sequential serial dictatorship: bake + group-8 speculation.
__global__ __launch_bounds__(256, 1) void sd_kernel(
    const uint32_t* __restrict__ pk_g, const short* __restrict__ ord_g,
    const short* __restrict__ td_g, float* __restrict__ out) {
    __shared__ __align__(16) uint4 s_pk4[50 * 64];   // 48 groups-of-4 + 2 pad
    __shared__ uint32_t s_match[NAG];
    __shared__ unsigned short s_og[NAG];
    __shared__ unsigned short s_td[NAG];

    const int t = threadIdx.x;
    if (t < NAG) {
        s_og[t] = ((const unsigned short*)ord_g)[t];
        s_td[t] = ((const unsigned short*)td_g)[t];
    }
    __syncthreads();

    // staging: s_pk4[g*64+lane] = {baked P[4g+i][lane]}_{i=0..3}
    // bake: pref j -> 97 (always-unavailable sentinel) if its owner dictates
    // before round r.
    for (int idx = t; idx < 48 * 64; idx += 256) {
        int g = idx >> 6, ln = idx & 63;
        uint32_t w[4];
        #pragma unroll
        for (int i = 0; i < 4; ++i) {
            int r = 4 * g + i;
            int a = (int)s_og[r];
            uint32_t x = pk_g[(a << 6) + ln];
            int opp = (a < 96) ? 96 : 0;
            uint32_t j1 = x & 0xFFFFu, j2 = x >> 16;
            if (j1 < 96u && (int)s_td[opp + j1] < r) j1 = 97u;
            if (j2 < 96u && (int)s_td[opp + j2] < r) j2 = 97u;
            w[i] = j1 | (j2 << 16);
        }
        s_pk4[idx] = make_uint4(w[0], w[1], w[2], w[3]);
    }
    __syncthreads();

    if (t < 64) {
        // chosen-only masks; bit33(hi)=sentinel-97 always set; bit32(hi)=
        // unmatch(96) kept clear by the &~(1<<32) in every update.
        uint64_t chWlo = 0, chWhi = (1ull << 33), chFlo = 0, chFhi = (1ull << 33);
        uint32_t c0 = 0xFFFFFFFFu, c1 = 0xFFFFFFFFu, c2 = 0xFFFFFFFFu;
        const uint4* ordq = (const uint4*)ord_g;        // 8 rounds per uint4

        // full two-slot query from live masks (cold path)
        auto FULLQ = [&](uint32_t P, uint64_t olo, uint64_t ohi) -> uint32_t {
            uint32_t j1 = P & 0xFFFFu;
            uint32_t b1 = (uint32_t)((((j1 < 64u) ? olo : ohi) >> (j1 & 63u)) & 1ull);
            unsigned long long m1 = __ballot(b1 == 0u);
            uint32_t j2 = P >> 16;
            uint32_t b2 = (uint32_t)((((j2 < 64u) ? olo : ohi) >> (j2 & 63u)) & 1ull);
            unsigned long long m2 = __ballot(b2 == 0u) & 0x1FFFFFFFFull;
            int k = (m1 != 0ull) ? (__ffsll(m1) - 1) : (63 + __ffsll(m2));
            uint32_t pc = (uint32_t)__builtin_amdgcn_readlane((int)P, k & 63);
            return (k >= 64) ? (pc >> 16) : (pc & 0xFFFFu);
        };

        uint4 Qa = s_pk4[t];                  // rounds 0..3
        uint4 Qb = s_pk4[64 + t];             // rounds 4..7
        uint4 oq = ordq[0];

        #pragma clang loop unroll(disable)
        for (int g = 0; g < 24; ++g) {
            // prefetch next group (2 tiles + ord), off-chain
            uint4 Qc = s_pk4[(2 * g + 2) * 64 + t];
            uint4 Qd = s_pk4[(2 * g + 3) * 64 + t];
            uint4 oqn = ordq[g + 1];          // g=23 overruns into td area: unused
            AEXT(oq)
            // Phase A: 8 independent speculative queries (hops pipeline)
            QPH(0, Qa.x) QPH(1, Qa.y) QPH(2, Qa.z) QPH(3, Qa.w)
            QPH(4, Qb.x) QPH(5, Qb.y) QPH(6, Qb.z) QPH(7, Qb.w)
            // Phase B: serial scalar resolve
            const int rb = (g << 3) & 63;
            uint32_t& cv = (g < 8) ? c0 : ((g < 16) ? c1 : c2);
            RESQ(0, Qa.x, rb + 0); RESQ(1, Qa.y, rb + 1);
            RESQ(2, Qa.z, rb + 2); RESQ(3, Qa.w, rb + 3);
            RESQ(4, Qb.x, rb + 4); RESQ(5, Qb.y, rb + 5);
            RESQ(6, Qb.z, rb + 6); RESQ(7, Qb.w, rb + 7);
            Qa = Qc; Qb = Qd; oq = oqn;
        }
        s_match[t] = c0; s_match[64 + t] = c1; s_match[128 + t] = c2;
    } else {
        // waves 1-3: zero-fill output concurrently with wave 0's loop
        for (int i = t - 64; i < 2352; i += 192)
            ((float4*)out)[i] = make_float4(0.f, 0.f, 0.f, 0.f);
        if (t == 64) out[9408] = 0.f;
    }
    __syncthreads();
    if (t < NAG) {
        uint32_t c = s_match[t];
        if (c != 0xFFFFFFFFu) out[c] = 1.0f;
    }
}

extern "C" void kernel_launch(void* const* d_in, const int* in_sizes, int n_in,
                              void* d_out, int out_size, void* d_ws, size_t ws_size,
                              hipStream_t stream) {
    const float* W = (const float*)d_in[0];
    const float* F = (const float*)d_in[1];
    const float* R = (const float*)d_in[2];
    float* out = (float*)d_out;

    uint32_t* packed = (uint32_t*)d_ws;                      // NAG*64 u32 = 48 KiB
    short* ord = (short*)((char*)d_ws + NAG * 64 * 4);       // 192 shorts
    short* td  = (short*)((char*)d_ws + NAG * 64 * 4 + NAG * 2);  // 192 shorts

    decode_kernel<<<2 * WB + RB, 256, 0, stream>>>(W, F, R, (short*)packed, ord, td);
    sd_kernel<<<1, 256, 0, stream>>>(packed, ord, td, out);
}